// Round 1
// baseline (24.261 us; speedup 1.0000x reference)
//
#include <hip/hip_runtime.h>
#include <hip/hip_bf16.h>

// Problem constants (fixed by setup_inputs): BS=2, NCAM=3, N=64, S=256
constexpr int S_IMG = 256;
constexpr int NPT   = 64;
constexpr int BC    = 6;      // BS*NCAM
constexpr int NCAM_ = 3;

// Each block: 256 threads, 2 pixels/thread (float2) -> 512 px = 2 image rows.
// Grid: BC * S/2 = 768 blocks.
__global__ __launch_bounds__(256) void render_blobs_kernel(
    const float* __restrict__ points,       // (BS,NCAM,N,2)
    const float* __restrict__ sigmas,       // (BS,N)
    const float* __restrict__ exponents,    // (BS,N)
    const float* __restrict__ intensities,  // (BS,N)
    const float* __restrict__ cam_sig,      // (BS,NCAM)
    const float* __restrict__ cam_exp,      // (BS,NCAM)
    const float* __restrict__ cam_int,      // (BS,NCAM)
    float* __restrict__ masks,              // (BC,S,S)
    float* __restrict__ blobs)              // (BC,N,S,S)
{
    const int blk = blockIdx.x;            // 0..767
    const int bc  = blk >> 7;              // / (S/2)
    const int y0  = (blk & 127) << 1;
    const int b   = bc / NCAM_;
    const int t   = threadIdx.x;

    __shared__ float spx[NPT], spy[NPT], sk[NPT], se[NPT], si[NPT];
    if (t < NPT) {
        const float inv = 1.0f / 128.0f;   // image_size/2 = 128
        float px = points[(bc * NPT + t) * 2 + 0];
        float py = points[(bc * NPT + t) * 2 + 1];
        px = fminf(fmaxf((px - 128.0f) * inv, -1.0f), 1.0f);
        py = fminf(fmaxf((py - 128.0f) * inv, -1.0f), 1.0f);
        float sg = sigmas[b * NPT + t] * cam_sig[bc];
        spx[t] = px;
        spy[t] = py;
        sk[t]  = 1.0f / (2.0f * sg * sg);
        se[t]  = exponents[b * NPT + t] * cam_exp[bc];
        si[t]  = intensities[b * NPT + t] * cam_int[bc];
    }
    __syncthreads();

    const int lin = t << 1;                // 0..510, even
    const int y   = y0 + (lin >> 8);
    const int x   = lin & 255;

    const float step = 2.0f / 255.0f;      // linspace(-1,1,256) step
    const float gx0  = fmaf((float)x, step, -1.0f);
    const float gx1  = gx0 + step;
    const float gy   = fmaf((float)y, step, -1.0f);

    float m0 = 0.0f, m1 = 0.0f;
    float* bp = blobs + (size_t)bc * NPT * S_IMG * S_IMG + (size_t)y * S_IMG + x;
    const size_t nstride = (size_t)S_IMG * S_IMG;

    #pragma unroll 4
    for (int n = 0; n < NPT; ++n) {
        float dx0 = gx0 - spx[n];
        float dx1 = gx1 - spx[n];
        float dy  = gy  - spy[n];
        float dy2 = dy * dy;
        float u0  = fmaf(dx0, dx0, dy2) * sk[n];
        float u1  = fmaf(dx1, dx1, dy2) * sk[n];
        float e   = se[n];
        // blob = exp(-(u^e)) ; u^e = exp2(e*log2 u) ; exp(-v) = exp2(-v*log2e)
        float v0 = exp2f(e * __log2f(u0));
        float v1 = exp2f(e * __log2f(u1));
        float b0 = exp2f(-1.4426950408889634f * v0);
        float b1 = exp2f(-1.4426950408889634f * v1);
        *reinterpret_cast<float2*>(bp + n * nstride) = make_float2(b0, b1);
        float it = si[n];
        m0 = fmaxf(m0, b0 * it);
        m1 = fmaxf(m1, b1 * it);
    }

    float2 mm = make_float2(fminf(m0, 1.0f), fminf(m1, 1.0f));
    *reinterpret_cast<float2*>(masks + (size_t)bc * S_IMG * S_IMG + (size_t)y * S_IMG + x) = mm;
}

extern "C" void kernel_launch(void* const* d_in, const int* in_sizes, int n_in,
                              void* d_out, int out_size, void* d_ws, size_t ws_size,
                              hipStream_t stream) {
    const float* points      = (const float*)d_in[0];
    const float* sigmas      = (const float*)d_in[1];
    const float* exponents   = (const float*)d_in[2];
    const float* intensities = (const float*)d_in[3];
    const float* cam_sig     = (const float*)d_in[4];
    const float* cam_exp     = (const float*)d_in[5];
    const float* cam_int     = (const float*)d_in[6];
    // d_in[7] = image_size (256), fixed by problem shape — hardcoded.

    float* masks = (float*)d_out;                                    // BC*S*S
    float* blobs = (float*)d_out + (size_t)BC * S_IMG * S_IMG;       // BC*NPT*S*S

    dim3 grid(BC * (S_IMG / 2));   // 768
    dim3 block(256);
    render_blobs_kernel<<<grid, block, 0, stream>>>(
        points, sigmas, exponents, intensities, cam_sig, cam_exp, cam_int,
        masks, blobs);
}